// Round 7
// baseline (6490.820 us; speedup 1.0000x reference)
//
#include <hip/hip_runtime.h>
#include <hip/hip_bf16.h>
#include <math.h>

typedef __hip_bfloat16 bf16;

static const int PRED  = 100000;
static const int TOTAL = 120000;
static const int ITEM  = 100000;
static const int NUI   = PRED + ITEM;    // 200000
static const int NODES = TOTAL + ITEM;   // 220000
#define BN_EPS 1e-5f

__device__ inline float lrelu(float v, float s) { return v > 0.f ? v : s * v; }

__device__ inline void atomicMaxF(float* addr, float v) {
  if (v >= 0.f) atomicMax((int*)addr, __float_as_int(v));
  else          atomicMin((unsigned int*)addr, __float_as_uint(v));
}

// ---------------- utility ----------------
__global__ void k_fill(float* p, float v, int n) {
  int i = blockIdx.x * blockDim.x + threadIdx.x;
  int st = gridDim.x * blockDim.x;
  for (; i < n; i += st) p[i] = v;
}

__global__ void k_lrelu_ip(float* p, size_t n, float slope) {
  size_t i = (size_t)blockIdx.x * blockDim.x + threadIdx.x;
  size_t st = (size_t)gridDim.x * blockDim.x;
  for (; i < n; i += st) p[i] = lrelu(p[i], slope);
}

// ---------------- batchnorm: one block per column, no atomics ----------------
__global__ void k_col_stats(const float* __restrict__ x, int n, float* __restrict__ sums) {
  __shared__ float s1[256], s2[256];
  int col = blockIdx.x;      // 0..63
  int t = threadIdx.x;
  float a = 0.f, b = 0.f;
  for (int r = t; r < n; r += 256) {
    float v = x[(size_t)r * 64 + col];
    a += v; b += v * v;
  }
  s1[t] = a; s2[t] = b;
  __syncthreads();
  for (int o = 128; o; o >>= 1) {
    if (t < o) { s1[t] += s1[t + o]; s2[t] += s2[t + o]; }
    __syncthreads();
  }
  if (t == 0) { sums[col] = s1[0]; sums[64 + col] = s2[0]; }
}

__global__ void k_bn_apply(const float* __restrict__ x, float* __restrict__ y,
                           const float* __restrict__ sums,
                           const float* __restrict__ g, const float* __restrict__ b,
                           int n, int relu) {
  size_t tot = (size_t)n * 64;
  size_t i = (size_t)blockIdx.x * blockDim.x + threadIdx.x;
  size_t st = (size_t)gridDim.x * blockDim.x;
  float inv_n = 1.f / (float)n;
  for (; i < tot; i += st) {
    int c = (int)(i & 63);
    float mean = sums[c] * inv_n;
    float var = fmaxf(sums[64 + c] * inv_n - mean * mean, 0.f);
    float o = (x[i] - mean) * rsqrtf(var + BN_EPS) * g[c] + b[c];
    if (relu) o = lrelu(o, 0.01f);
    y[i] = o;
  }
}

// bn0: rows [0,TOTAL) -> e_tot; rows [TOTAL,NODES) -> uie[PRED..NUI); rows [0,PRED) also -> uie
__global__ void k_bn0_apply(const float* __restrict__ x, float* __restrict__ e_tot,
                            float* __restrict__ uie, const float* __restrict__ sums,
                            const float* __restrict__ g, const float* __restrict__ b) {
  size_t tot = (size_t)NODES * 64;
  size_t i = (size_t)blockIdx.x * blockDim.x + threadIdx.x;
  size_t st = (size_t)gridDim.x * blockDim.x;
  float inv_n = 1.f / (float)NODES;
  for (; i < tot; i += st) {
    int c = (int)(i & 63);
    size_t row = i >> 6;
    float mean = sums[c] * inv_n;
    float var = fmaxf(sums[64 + c] * inv_n - mean * mean, 0.f);
    float o = (x[i] - mean) * rsqrtf(var + BN_EPS) * g[c] + b[c];
    if (row < (size_t)TOTAL) e_tot[i] = o;
    else uie[((row - TOTAL) + PRED) * 64 + c] = o;
    if (row < (size_t)PRED) uie[i] = o;
  }
}

// ---------------- GEMM: C[n x 64] = A[n x 64] @ W[64 x 64] (+bias)(+=)(lrelu) ----------------
__global__ __launch_bounds__(256) void k_gemm64(const float* __restrict__ A,
                                                const float* __restrict__ Wm,
                                                const float* __restrict__ bias,
                                                float* __restrict__ C,
                                                int n, int accumulate, int relu) {
  __shared__ float AsT[64][68];
  __shared__ float Ws[64][68];
  int t = threadIdx.x;
  int row0 = blockIdx.x * 64;
  for (int i = t; i < 4096; i += 256) {
    int r = i >> 6, c = i & 63;
    Ws[r][c] = Wm[i];
    int gr = row0 + r;
    AsT[c][r] = (gr < n) ? A[(size_t)gr * 64 + c] : 0.f;
  }
  __syncthreads();
  int cg = (t & 15) * 4;
  int rg = (t >> 4) * 4;
  float acc[4][4];
  float b0 = 0.f, b1 = 0.f, b2v = 0.f, b3 = 0.f;
  if (bias) { b0 = bias[cg]; b1 = bias[cg + 1]; b2v = bias[cg + 2]; b3 = bias[cg + 3]; }
  for (int i = 0; i < 4; i++) { acc[i][0] = b0; acc[i][1] = b1; acc[i][2] = b2v; acc[i][3] = b3; }
  for (int k = 0; k < 64; ++k) {
    float4 w = *(const float4*)&Ws[k][cg];
    float4 a = *(const float4*)&AsT[k][rg];
    acc[0][0] += a.x * w.x; acc[0][1] += a.x * w.y; acc[0][2] += a.x * w.z; acc[0][3] += a.x * w.w;
    acc[1][0] += a.y * w.x; acc[1][1] += a.y * w.y; acc[1][2] += a.y * w.z; acc[1][3] += a.y * w.w;
    acc[2][0] += a.z * w.x; acc[2][1] += a.z * w.y; acc[2][2] += a.z * w.z; acc[2][3] += a.z * w.w;
    acc[3][0] += a.w * w.x; acc[3][1] += a.w * w.y; acc[3][2] += a.w * w.z; acc[3][3] += a.w * w.w;
  }
  for (int i = 0; i < 4; ++i) {
    int gr = row0 + rg + i;
    if (gr < n) {
      float4 o; o.x = acc[i][0]; o.y = acc[i][1]; o.z = acc[i][2]; o.w = acc[i][3];
      if (accumulate) {
        float4 p = *(const float4*)&C[(size_t)gr * 64 + cg];
        o.x += p.x; o.y += p.y; o.z += p.z; o.w += p.w;
      }
      if (relu) { o.x = lrelu(o.x, 0.01f); o.y = lrelu(o.y, 0.01f); o.z = lrelu(o.z, 0.01f); o.w = lrelu(o.w, 0.01f); }
      *(float4*)&C[(size_t)gr * 64 + cg] = o;
    }
  }
}

// ---------------- GAT edge kernels (wave per edge) ----------------
__global__ void k_gat_edge(const float* __restrict__ fs, const float* __restrict__ fd,
                           const float* __restrict__ attn,
                           const int* __restrict__ src, const int* __restrict__ dst,
                           float* __restrict__ e_edge, float* __restrict__ m, int E) {
  int lane = threadIdx.x & 63;
  int wid = (blockIdx.x * blockDim.x + threadIdx.x) >> 6;
  int nw = (gridDim.x * blockDim.x) >> 6;
  float ak = attn[lane];
  for (int e = wid; e < E; e += nw) {
    int s = src[e], d = dst[e];
    float v = fs[(size_t)s * 64 + lane] + fd[(size_t)d * 64 + lane];
    float p = ak * lrelu(v, 0.2f);
    for (int o = 32; o; o >>= 1) p += __shfl_xor(p, o);
    if (lane == 0) {
      e_edge[e] = p;
      atomicMaxF(&m[d], p);
    }
  }
}

__global__ void k_gat_soft(float* __restrict__ e_edge, const float* __restrict__ m,
                           const int* __restrict__ dst, float* __restrict__ denom, int E) {
  int i = blockIdx.x * blockDim.x + threadIdx.x;
  int st = gridDim.x * blockDim.x;
  for (; i < E; i += st) {
    int d = dst[i];
    float ex = expf(e_edge[i] - m[d]);
    e_edge[i] = ex;
    atomicAdd(&denom[d], ex);
  }
}

__global__ void k_gat_scat(const float* __restrict__ fs, const float* __restrict__ ex,
                           const float* __restrict__ denom,
                           const int* __restrict__ src, const int* __restrict__ dst,
                           float* __restrict__ out, int E) {
  int lane = threadIdx.x & 63;
  int wid = (blockIdx.x * blockDim.x + threadIdx.x) >> 6;
  int nw = (gridDim.x * blockDim.x) >> 6;
  for (int e = wid; e < E; e += nw) {
    int s = src[e], d = dst[e];
    float alpha = ex[e] / denom[d];
    atomicAdd(&out[(size_t)d * 64 + lane], alpha * fs[(size_t)s * 64 + lane]);
  }
}

// ---------------- Cheb kernels ----------------
__global__ void k_deg(const int* __restrict__ dst, float* __restrict__ deg, int E) {
  int i = blockIdx.x * blockDim.x + threadIdx.x;
  int st = gridDim.x * blockDim.x;
  for (; i < E; i += st) atomicAdd(&deg[dst[i]], 1.0f);
}

__global__ void k_rsqrt_clip(float* deg, int n) {
  int i = blockIdx.x * blockDim.x + threadIdx.x;
  int st = gridDim.x * blockDim.x;
  for (; i < n; i += st) deg[i] = rsqrtf(fmaxf(deg[i], 1.0f));
}

__global__ void k_cheb_scat(const float* __restrict__ v, const float* __restrict__ dinv,
                            const int* __restrict__ src, const int* __restrict__ dst,
                            float* __restrict__ av, int E) {
  int lane = threadIdx.x & 63;
  int wid = (blockIdx.x * blockDim.x + threadIdx.x) >> 6;
  int nw = (gridDim.x * blockDim.x) >> 6;
  for (int e = wid; e < E; e += nw) {
    int s = src[e], d = dst[e];
    float norm = dinv[s] * dinv[d];
    atomicAdd(&av[(size_t)d * 64 + lane], norm * v[(size_t)s * 64 + lane]);
  }
}

__global__ void k_cheb_c1(const float* __restrict__ T0, float* __restrict__ av,
                          size_t n, const float* __restrict__ lamf) {
  float c = 2.f / lamf[0];
  size_t i = (size_t)blockIdx.x * blockDim.x + threadIdx.x;
  size_t st = (size_t)gridDim.x * blockDim.x;
  for (; i < n; i += st) {
    float t0 = T0[i];
    av[i] = c * (t0 - av[i]) - t0;
  }
}

__global__ void k_cheb_c2(const float* __restrict__ T0, const float* __restrict__ T1,
                          float* __restrict__ av, size_t n, const float* __restrict__ lamf) {
  float c = 2.f / lamf[0];
  size_t i = (size_t)blockIdx.x * blockDim.x + threadIdx.x;
  size_t st = (size_t)gridDim.x * blockDim.x;
  for (; i < n; i += st) {
    float t1 = T1[i];
    av[i] = 2.f * (c * (t1 - av[i]) - t1) - T0[i];
  }
}

// ---------------- misc fused (wave per row) ----------------
__global__ void k_mask_select(const float* __restrict__ i2u, const float* __restrict__ pred,
                              float* __restrict__ out, int n) {
  int lane = threadIdx.x & 63;
  int wid = (blockIdx.x * blockDim.x + threadIdx.x) >> 6;
  int nw = (gridDim.x * blockDim.x) >> 6;
  for (int r = wid; r < n; r += nw) {
    float v = i2u[(size_t)r * 64 + lane];
    float s = v;
    for (int o = 32; o; o >>= 1) s += __shfl_xor(s, o);
    out[(size_t)r * 64 + lane] = (s != 0.f) ? v : pred[(size_t)r * 64 + lane];
  }
}

// out = a * b * softmax_row(a)
__global__ void k_softmax_mul(const float* __restrict__ a, const float* __restrict__ b,
                              float* __restrict__ out, int n) {
  int lane = threadIdx.x & 63;
  int wid = (blockIdx.x * blockDim.x + threadIdx.x) >> 6;
  int nw = (gridDim.x * blockDim.x) >> 6;
  for (int r = wid; r < n; r += nw) {
    size_t idx = (size_t)r * 64 + lane;
    float av = a[idx];
    float mx = av;
    for (int o = 32; o; o >>= 1) mx = fmaxf(mx, __shfl_xor(mx, o));
    float e = expf(av - mx);
    float s = e;
    for (int o = 32; o; o >>= 1) s += __shfl_xor(s, o);
    out[idx] = av * b[idx] * (e / s);
  }
}

// ---------------- host ----------------
extern "C" void kernel_launch(void* const* d_in, const int* in_sizes, int n_in,
                              void* d_out, int out_size, void* d_ws, size_t ws_size,
                              hipStream_t stream) {
  const float* emb      = (const float*)d_in[0];
  const float* bn0_g    = (const float*)d_in[1];
  const float* bn0_b    = (const float*)d_in[2];
  const float* gat_Wl   = (const float*)d_in[3];
  const float* gat_bl   = (const float*)d_in[4];
  const float* gat_Wr   = (const float*)d_in[5];
  const float* gat_br   = (const float*)d_in[6];
  const float* gat_attn = (const float*)d_in[7];
  const float* cheb_W   = (const float*)d_in[8];
  const float* cheb_b   = (const float*)d_in[9];
  const float* mlp_W    = (const float*)d_in[10];
  const float* mlp_b    = (const float*)d_in[11];
  const float* mlp_g    = (const float*)d_in[12];
  const float* mlp_beta = (const float*)d_in[13];
  const float* lam      = (const float*)d_in[14];
  const int* u2i_src = (const int*)d_in[15];
  const int* u2i_dst = (const int*)d_in[16];
  const int* rc_src  = (const int*)d_in[17];
  const int* rc_dst  = (const int*)d_in[18];
  const int* i2u_src = (const int*)d_in[19];
  const int* i2u_dst = (const int*)d_in[20];
  const int* sn_src  = (const int*)d_in[22];
  const int* sn_dst  = (const int*)d_in[23];
  const int* snn_src = (const int*)d_in[24];
  const int* snn_dst = (const int*)d_in[25];
  int E_u2i = in_sizes[15], E_rc = in_sizes[17], E_i2u = in_sizes[19];
  int E_sn = in_sizes[22], E_snn = in_sizes[24];

  float* Wp = (float*)d_ws;
  size_t off = 0;
  auto alloc = [&](size_t nf) { float* p = Wp + off; off += nf; return p; };
  float* e_tot = alloc((size_t)TOTAL * 64);     // 30.7 MB
  float* POOL  = alloc((size_t)600000 * 64);    // 153.6 MB
  float* e_edge = alloc(1500000);
  float* m_buf  = alloc(NUI);
  float* denom  = alloc(NUI);
  float* deg    = alloc(TOTAL);
  float* sums   = alloc(128);
  // total ~192.4 MB

  auto R = [&](size_t row) { return POOL + row * 64; };
  float* outP = (float*)d_out;                  // f32 output!
  float* outS = outP + (size_t)PRED * 64;

  auto gemm = [&](const float* A, const float* Wm, const float* bias, float* C, int n, int acc, int relu) {
    k_gemm64<<<(n + 63) / 64, 256, 0, stream>>>(A, Wm, bias, C, n, acc, relu);
  };
  auto gat_edges = [&](int i, float* fs, float* fd, int n, const int* src, const int* dst,
                       int E, float* out) {
    k_fill<<<256, 256, 0, stream>>>(m_buf, -INFINITY, n);
    hipMemsetAsync(denom, 0, (size_t)n * 4, stream);
    k_gat_edge<<<2048, 256, 0, stream>>>(fs, fd, gat_attn + i * 64, src, dst, e_edge, m_buf, E);
    k_gat_soft<<<2048, 256, 0, stream>>>(e_edge, m_buf, dst, denom, E);
    hipMemsetAsync(out, 0, (size_t)n * 64 * 4, stream);
    k_gat_scat<<<2048, 256, 0, stream>>>(fs, e_edge, denom, src, dst, out, E);
    k_lrelu_ip<<<2048, 256, 0, stream>>>(out, (size_t)n * 64, 0.01f);
  };

  // ---- bn0 ----
  k_col_stats<<<64, 256, 0, stream>>>(emb, NODES, sums);
  k_bn0_apply<<<2048, 256, 0, stream>>>(emb, e_tot, R(0), sums, bn0_g, bn0_b);

  // ---- gat0: u2i_emb -> R(0) (in-place over uie) ----
  gemm(R(0), gat_Wl + 0 * 4096, gat_bl + 0, R(200000), NUI, 0, 0);
  gemm(R(0), gat_Wr + 0 * 4096, gat_br + 0, R(400000), NUI, 0, 0);
  gat_edges(0, R(200000), R(400000), NUI, u2i_src, u2i_dst, E_u2i, R(0));

  // ---- gat1: iie -> R(0)[:PRED] ----
  gemm(R(0), gat_Wl + 1 * 4096, gat_bl + 64, R(200000), NUI, 0, 0);
  gemm(R(0), gat_Wr + 1 * 4096, gat_br + 64, R(400000), NUI, 0, 0);
  gat_edges(1, R(200000), R(400000), NUI, rc_src, rc_dst, E_rc, R(0));

  // ---- gat2: i2u_emb -> R(300000) ----
  gemm(e_tot, gat_Wl + 2 * 4096, gat_bl + 128, R(200000), PRED, 0, 0);
  gemm(e_tot, gat_Wr + 2 * 4096, gat_br + 128, R(400000), PRED, 0, 0);
  gat_edges(2, R(200000), R(400000), PRED, i2u_src, i2u_dst, E_i2u, R(300000));

  // ---- soc -> R(400000) ----
  k_mask_select<<<2048, 256, 0, stream>>>(R(300000), e_tot, R(400000), PRED);

  // ---- gat3: sie -> R(300000) ----
  gemm(R(400000), gat_Wl + 3 * 4096, gat_bl + 192, R(200000), PRED, 0, 0);
  gemm(R(400000), gat_Wr + 3 * 4096, gat_br + 192, R(500000), PRED, 0, 0);
  gat_edges(3, R(200000), R(500000), PRED, sn_src, sn_dst, E_sn, R(300000));

  // ---- mlp0: user_item -> R(0)[:PRED] (via scratch R(100000)) ----
  gemm(R(0), mlp_W + 0 * 8192, mlp_b + 0, R(100000), PRED, 0, 0);
  gemm(R(300000), mlp_W + 0 * 8192 + 4096, nullptr, R(100000), PRED, 1, 0);
  k_col_stats<<<64, 256, 0, stream>>>(R(100000), PRED, sums);
  k_bn_apply<<<2048, 256, 0, stream>>>(R(100000), R(0), sums, mlp_g + 0, mlp_beta + 0, PRED, 1);

  // ---- cheb degrees ----
  hipMemsetAsync(deg, 0, (size_t)TOTAL * 4, stream);
  k_deg<<<2048, 256, 0, stream>>>(snn_dst, deg, E_snn);
  k_rsqrt_clip<<<256, 256, 0, stream>>>(deg, TOTAL);

  auto cheb = [&](const float* T0, float* T1, float* T2, float* outC) {
    hipMemsetAsync(T1, 0, (size_t)TOTAL * 64 * 4, stream);
    k_cheb_scat<<<2048, 256, 0, stream>>>(T0, deg, snn_src, snn_dst, T1, E_snn);
    k_cheb_c1<<<2048, 256, 0, stream>>>(T0, T1, (size_t)TOTAL * 64, lam);
    hipMemsetAsync(T2, 0, (size_t)TOTAL * 64 * 4, stream);
    k_cheb_scat<<<2048, 256, 0, stream>>>(T1, deg, snn_src, snn_dst, T2, E_snn);
    k_cheb_c2<<<2048, 256, 0, stream>>>(T0, T1, T2, (size_t)TOTAL * 64, lam);
    gemm(T0, cheb_W + 0,    cheb_b, outC, TOTAL, 0, 0);
    gemm(T1, cheb_W + 4096, nullptr, outC, TOTAL, 1, 0);
    gemm(T2, cheb_W + 8192, nullptr, outC, TOTAL, 1, 1);
  };
  cheb(e_tot, R(100000), R(220000), R(340000));       // h1 -> R(340000)
  cheb(R(340000), R(100000), R(220000), R(460000));   // h2 -> R(460000)

  // ---- gat4: user_social -> R(460000) ----
  gemm(R(460000), gat_Wl + 4 * 4096, gat_bl + 256, R(100000), TOTAL, 0, 0);
  gemm(R(460000), gat_Wr + 4 * 4096, gat_br + 256, R(220000), TOTAL, 0, 0);
  gat_edges(4, R(100000), R(220000), TOTAL, snn_src, snn_dst, E_snn, R(460000));

  // ---- mlp1: h_uP -> R(100000) ----
  gemm(R(0), mlp_W + 1 * 8192, mlp_b + 64, R(100000), PRED, 0, 0);
  gemm(e_tot, mlp_W + 1 * 8192 + 4096, nullptr, R(100000), PRED, 1, 0);
  k_col_stats<<<64, 256, 0, stream>>>(R(100000), PRED, sums);
  k_bn_apply<<<2048, 256, 0, stream>>>(R(100000), R(100000), sums, mlp_g + 64, mlp_beta + 64, PRED, 1);

  // ---- mlp2: h_uS -> R(200000) ----
  gemm(R(460000), mlp_W + 2 * 8192, mlp_b + 128, R(200000), PRED, 0, 0);
  gemm(e_tot, mlp_W + 2 * 8192 + 4096, nullptr, R(200000), PRED, 1, 0);
  k_col_stats<<<64, 256, 0, stream>>>(R(200000), PRED, sums);
  k_bn_apply<<<2048, 256, 0, stream>>>(R(200000), R(200000), sums, mlp_g + 128, mlp_beta + 128, PRED, 1);

  // ---- final P ----
  k_softmax_mul<<<2048, 256, 0, stream>>>(R(100000), R(200000), R(300000), PRED);
  gemm(R(300000), mlp_W + 3 * 8192, mlp_b + 192, R(400000), PRED, 0, 0);
  gemm(R(100000), mlp_W + 3 * 8192 + 4096, nullptr, R(400000), PRED, 1, 0);
  k_col_stats<<<64, 256, 0, stream>>>(R(400000), PRED, sums);
  k_bn_apply<<<2048, 256, 0, stream>>>(R(400000), outP, sums, mlp_g + 192, mlp_beta + 192, PRED, 1);

  // ---- final S ----
  k_softmax_mul<<<2048, 256, 0, stream>>>(R(200000), R(100000), R(300000), PRED);
  gemm(R(300000), mlp_W + 4 * 8192, mlp_b + 256, R(400000), PRED, 0, 0);
  gemm(R(200000), mlp_W + 4 * 8192 + 4096, nullptr, R(400000), PRED, 1, 0);
  k_col_stats<<<64, 256, 0, stream>>>(R(400000), PRED, sums);
  k_bn_apply<<<2048, 256, 0, stream>>>(R(400000), outS, sums, mlp_g + 256, mlp_beta + 256, PRED, 1);
}

// Round 8
// 5536.414 us; speedup vs baseline: 1.1724x; 1.1724x over previous
//
#include <hip/hip_runtime.h>
#include <hip/hip_bf16.h>
#include <math.h>

typedef __hip_bfloat16 bf16;

static const int PRED  = 100000;
static const int TOTAL = 120000;
static const int ITEM  = 100000;
static const int NUI   = PRED + ITEM;    // 200000
static const int NODES = TOTAL + ITEM;   // 220000
#define BN_EPS 1e-5f

__device__ inline float lrelu(float v, float s) { return v > 0.f ? v : s * v; }

__device__ inline void atomicMaxF(float* addr, float v) {
  if (v >= 0.f) atomicMax((int*)addr, __float_as_int(v));
  else          atomicMin((unsigned int*)addr, __float_as_uint(v));
}

// ---------------- utility ----------------
__global__ void k_fill(float* p, float v, int n) {
  int i = blockIdx.x * blockDim.x + threadIdx.x;
  int st = gridDim.x * blockDim.x;
  for (; i < n; i += st) p[i] = v;
}

__global__ void k_lrelu_ip(float* p, size_t n, float slope) {
  size_t i = (size_t)blockIdx.x * blockDim.x + threadIdx.x;
  size_t st = (size_t)gridDim.x * blockDim.x;
  for (; i < n; i += st) p[i] = lrelu(p[i], slope);
}

// ---------------- batchnorm: coalesced grid-strided stats + per-block atomics ----------------
// block = 256 (4 rows x 64 cols per iter); lane c of each quad-row reads column c -> coalesced.
__global__ void k_bn_stats(const float* __restrict__ x, int n, float* __restrict__ sums) {
  __shared__ float ls[256], ls2[256];
  int t = threadIdx.x;
  int col = t & 63;
  float s = 0.f, s2 = 0.f;
  for (int r = blockIdx.x * 4 + (t >> 6); r < n; r += gridDim.x * 4) {
    float v = x[(size_t)r * 64 + col];
    s += v; s2 += v * v;
  }
  ls[t] = s; ls2[t] = s2;
  __syncthreads();
  if (t < 64) {
    atomicAdd(&sums[t],      ls[t] + ls[t + 64] + ls[t + 128] + ls[t + 192]);
    atomicAdd(&sums[64 + t], ls2[t] + ls2[t + 64] + ls2[t + 128] + ls2[t + 192]);
  }
}

__global__ void k_bn_apply(const float* __restrict__ x, float* __restrict__ y,
                           const float* __restrict__ sums,
                           const float* __restrict__ g, const float* __restrict__ b,
                           int n, int relu) {
  size_t tot = (size_t)n * 64;
  size_t i = (size_t)blockIdx.x * blockDim.x + threadIdx.x;
  size_t st = (size_t)gridDim.x * blockDim.x;
  float inv_n = 1.f / (float)n;
  for (; i < tot; i += st) {
    int c = (int)(i & 63);
    float mean = sums[c] * inv_n;
    float var = fmaxf(sums[64 + c] * inv_n - mean * mean, 0.f);
    float o = (x[i] - mean) * rsqrtf(var + BN_EPS) * g[c] + b[c];
    if (relu) o = lrelu(o, 0.01f);
    y[i] = o;
  }
}

// bn0: rows [0,TOTAL) -> e_tot; rows [TOTAL,NODES) -> uie[PRED..NUI); rows [0,PRED) also -> uie
__global__ void k_bn0_apply(const float* __restrict__ x, float* __restrict__ e_tot,
                            float* __restrict__ uie, const float* __restrict__ sums,
                            const float* __restrict__ g, const float* __restrict__ b) {
  size_t tot = (size_t)NODES * 64;
  size_t i = (size_t)blockIdx.x * blockDim.x + threadIdx.x;
  size_t st = (size_t)gridDim.x * blockDim.x;
  float inv_n = 1.f / (float)NODES;
  for (; i < tot; i += st) {
    int c = (int)(i & 63);
    size_t row = i >> 6;
    float mean = sums[c] * inv_n;
    float var = fmaxf(sums[64 + c] * inv_n - mean * mean, 0.f);
    float o = (x[i] - mean) * rsqrtf(var + BN_EPS) * g[c] + b[c];
    if (row < (size_t)TOTAL) e_tot[i] = o;
    else uie[((row - TOTAL) + PRED) * 64 + c] = o;
    if (row < (size_t)PRED) uie[i] = o;
  }
}

// ---------------- GEMM: C[n x 64] = A[n x 64] @ W[64 x 64] (+bias)(+=)(lrelu) ----------------
__global__ __launch_bounds__(256) void k_gemm64(const float* __restrict__ A,
                                                const float* __restrict__ Wm,
                                                const float* __restrict__ bias,
                                                float* __restrict__ C,
                                                int n, int accumulate, int relu) {
  __shared__ float AsT[64][68];
  __shared__ float Ws[64][68];
  int t = threadIdx.x;
  int row0 = blockIdx.x * 64;
  for (int i = t; i < 4096; i += 256) {
    int r = i >> 6, c = i & 63;
    Ws[r][c] = Wm[i];
    int gr = row0 + r;
    AsT[c][r] = (gr < n) ? A[(size_t)gr * 64 + c] : 0.f;
  }
  __syncthreads();
  int cg = (t & 15) * 4;
  int rg = (t >> 4) * 4;
  float acc[4][4];
  float b0 = 0.f, b1 = 0.f, b2v = 0.f, b3 = 0.f;
  if (bias) { b0 = bias[cg]; b1 = bias[cg + 1]; b2v = bias[cg + 2]; b3 = bias[cg + 3]; }
  for (int i = 0; i < 4; i++) { acc[i][0] = b0; acc[i][1] = b1; acc[i][2] = b2v; acc[i][3] = b3; }
  for (int k = 0; k < 64; ++k) {
    float4 w = *(const float4*)&Ws[k][cg];
    float4 a = *(const float4*)&AsT[k][rg];
    acc[0][0] += a.x * w.x; acc[0][1] += a.x * w.y; acc[0][2] += a.x * w.z; acc[0][3] += a.x * w.w;
    acc[1][0] += a.y * w.x; acc[1][1] += a.y * w.y; acc[1][2] += a.y * w.z; acc[1][3] += a.y * w.w;
    acc[2][0] += a.z * w.x; acc[2][1] += a.z * w.y; acc[2][2] += a.z * w.z; acc[2][3] += a.z * w.w;
    acc[3][0] += a.w * w.x; acc[3][1] += a.w * w.y; acc[3][2] += a.w * w.z; acc[3][3] += a.w * w.w;
  }
  for (int i = 0; i < 4; ++i) {
    int gr = row0 + rg + i;
    if (gr < n) {
      float4 o; o.x = acc[i][0]; o.y = acc[i][1]; o.z = acc[i][2]; o.w = acc[i][3];
      if (accumulate) {
        float4 p = *(const float4*)&C[(size_t)gr * 64 + cg];
        o.x += p.x; o.y += p.y; o.z += p.z; o.w += p.w;
      }
      if (relu) { o.x = lrelu(o.x, 0.01f); o.y = lrelu(o.y, 0.01f); o.z = lrelu(o.z, 0.01f); o.w = lrelu(o.w, 0.01f); }
      *(float4*)&C[(size_t)gr * 64 + cg] = o;
    }
  }
}

// ---------------- GAT edge kernels (wave per edge) ----------------
__global__ void k_gat_edge(const float* __restrict__ fs, const float* __restrict__ fd,
                           const float* __restrict__ attn,
                           const int* __restrict__ src, const int* __restrict__ dst,
                           float* __restrict__ e_edge, float* __restrict__ m, int E) {
  int lane = threadIdx.x & 63;
  int wid = (blockIdx.x * blockDim.x + threadIdx.x) >> 6;
  int nw = (gridDim.x * blockDim.x) >> 6;
  float ak = attn[lane];
  for (int e = wid; e < E; e += nw) {
    int s = src[e], d = dst[e];
    float v = fs[(size_t)s * 64 + lane] + fd[(size_t)d * 64 + lane];
    float p = ak * lrelu(v, 0.2f);
    for (int o = 32; o; o >>= 1) p += __shfl_xor(p, o);
    if (lane == 0) {
      e_edge[e] = p;
      atomicMaxF(&m[d], p);
    }
  }
}

__global__ void k_gat_soft(float* __restrict__ e_edge, const float* __restrict__ m,
                           const int* __restrict__ dst, float* __restrict__ denom, int E) {
  int i = blockIdx.x * blockDim.x + threadIdx.x;
  int st = gridDim.x * blockDim.x;
  for (; i < E; i += st) {
    int d = dst[i];
    float ex = expf(e_edge[i] - m[d]);
    e_edge[i] = ex;
    atomicAdd(&denom[d], ex);
  }
}

__global__ void k_gat_scat(const float* __restrict__ fs, const float* __restrict__ ex,
                           const float* __restrict__ denom,
                           const int* __restrict__ src, const int* __restrict__ dst,
                           float* __restrict__ out, int E) {
  int lane = threadIdx.x & 63;
  int wid = (blockIdx.x * blockDim.x + threadIdx.x) >> 6;
  int nw = (gridDim.x * blockDim.x) >> 6;
  for (int e = wid; e < E; e += nw) {
    int s = src[e], d = dst[e];
    float alpha = ex[e] / denom[d];
    atomicAdd(&out[(size_t)d * 64 + lane], alpha * fs[(size_t)s * 64 + lane]);
  }
}

// ---------------- Cheb kernels ----------------
__global__ void k_deg(const int* __restrict__ dst, float* __restrict__ deg, int E) {
  int i = blockIdx.x * blockDim.x + threadIdx.x;
  int st = gridDim.x * blockDim.x;
  for (; i < E; i += st) atomicAdd(&deg[dst[i]], 1.0f);
}

__global__ void k_rsqrt_clip(float* deg, int n) {
  int i = blockIdx.x * blockDim.x + threadIdx.x;
  int st = gridDim.x * blockDim.x;
  for (; i < n; i += st) deg[i] = rsqrtf(fmaxf(deg[i], 1.0f));
}

__global__ void k_cheb_scat(const float* __restrict__ v, const float* __restrict__ dinv,
                            const int* __restrict__ src, const int* __restrict__ dst,
                            float* __restrict__ av, int E) {
  int lane = threadIdx.x & 63;
  int wid = (blockIdx.x * blockDim.x + threadIdx.x) >> 6;
  int nw = (gridDim.x * blockDim.x) >> 6;
  for (int e = wid; e < E; e += nw) {
    int s = src[e], d = dst[e];
    float norm = dinv[s] * dinv[d];
    atomicAdd(&av[(size_t)d * 64 + lane], norm * v[(size_t)s * 64 + lane]);
  }
}

__global__ void k_cheb_c1(const float* __restrict__ T0, float* __restrict__ av,
                          size_t n, const float* __restrict__ lamf) {
  float c = 2.f / lamf[0];
  size_t i = (size_t)blockIdx.x * blockDim.x + threadIdx.x;
  size_t st = (size_t)gridDim.x * blockDim.x;
  for (; i < n; i += st) {
    float t0 = T0[i];
    av[i] = c * (t0 - av[i]) - t0;
  }
}

__global__ void k_cheb_c2(const float* __restrict__ T0, const float* __restrict__ T1,
                          float* __restrict__ av, size_t n, const float* __restrict__ lamf) {
  float c = 2.f / lamf[0];
  size_t i = (size_t)blockIdx.x * blockDim.x + threadIdx.x;
  size_t st = (size_t)gridDim.x * blockDim.x;
  for (; i < n; i += st) {
    float t1 = T1[i];
    av[i] = 2.f * (c * (t1 - av[i]) - t1) - T0[i];
  }
}

// ---------------- misc fused (wave per row) ----------------
__global__ void k_mask_select(const float* __restrict__ i2u, const float* __restrict__ pred,
                              float* __restrict__ out, int n) {
  int lane = threadIdx.x & 63;
  int wid = (blockIdx.x * blockDim.x + threadIdx.x) >> 6;
  int nw = (gridDim.x * blockDim.x) >> 6;
  for (int r = wid; r < n; r += nw) {
    float v = i2u[(size_t)r * 64 + lane];
    float s = v;
    for (int o = 32; o; o >>= 1) s += __shfl_xor(s, o);
    out[(size_t)r * 64 + lane] = (s != 0.f) ? v : pred[(size_t)r * 64 + lane];
  }
}

// out = a * b * softmax_row(a)
__global__ void k_softmax_mul(const float* __restrict__ a, const float* __restrict__ b,
                              float* __restrict__ out, int n) {
  int lane = threadIdx.x & 63;
  int wid = (blockIdx.x * blockDim.x + threadIdx.x) >> 6;
  int nw = (gridDim.x * blockDim.x) >> 6;
  for (int r = wid; r < n; r += nw) {
    size_t idx = (size_t)r * 64 + lane;
    float av = a[idx];
    float mx = av;
    for (int o = 32; o; o >>= 1) mx = fmaxf(mx, __shfl_xor(mx, o));
    float e = expf(av - mx);
    float s = e;
    for (int o = 32; o; o >>= 1) s += __shfl_xor(s, o);
    out[idx] = av * b[idx] * (e / s);
  }
}

// ---------------- host ----------------
extern "C" void kernel_launch(void* const* d_in, const int* in_sizes, int n_in,
                              void* d_out, int out_size, void* d_ws, size_t ws_size,
                              hipStream_t stream) {
  const float* emb      = (const float*)d_in[0];
  const float* bn0_g    = (const float*)d_in[1];
  const float* bn0_b    = (const float*)d_in[2];
  const float* gat_Wl   = (const float*)d_in[3];
  const float* gat_bl   = (const float*)d_in[4];
  const float* gat_Wr   = (const float*)d_in[5];
  const float* gat_br   = (const float*)d_in[6];
  const float* gat_attn = (const float*)d_in[7];
  const float* cheb_W   = (const float*)d_in[8];
  const float* cheb_b   = (const float*)d_in[9];
  const float* mlp_W    = (const float*)d_in[10];
  const float* mlp_b    = (const float*)d_in[11];
  const float* mlp_g    = (const float*)d_in[12];
  const float* mlp_beta = (const float*)d_in[13];
  const float* lam      = (const float*)d_in[14];
  const int* u2i_src = (const int*)d_in[15];
  const int* u2i_dst = (const int*)d_in[16];
  const int* rc_src  = (const int*)d_in[17];
  const int* rc_dst  = (const int*)d_in[18];
  const int* i2u_src = (const int*)d_in[19];
  const int* i2u_dst = (const int*)d_in[20];
  const int* sn_src  = (const int*)d_in[22];
  const int* sn_dst  = (const int*)d_in[23];
  const int* snn_src = (const int*)d_in[24];
  const int* snn_dst = (const int*)d_in[25];
  int E_u2i = in_sizes[15], E_rc = in_sizes[17], E_i2u = in_sizes[19];
  int E_sn = in_sizes[22], E_snn = in_sizes[24];

  float* Wp = (float*)d_ws;
  size_t off = 0;
  auto alloc = [&](size_t nf) { float* p = Wp + off; off += nf; return p; };
  float* e_tot = alloc((size_t)TOTAL * 64);     // 30.7 MB
  float* POOL  = alloc((size_t)600000 * 64);    // 153.6 MB
  float* e_edge = alloc(1500000);
  float* m_buf  = alloc(NUI);
  float* denom  = alloc(NUI);
  float* deg    = alloc(TOTAL);
  float* sums   = alloc(128);
  // total ~192.4 MB

  auto R = [&](size_t row) { return POOL + row * 64; };
  float* outP = (float*)d_out;                  // f32 output
  float* outS = outP + (size_t)PRED * 64;

  auto gemm = [&](const float* A, const float* Wm, const float* bias, float* C, int n, int acc, int relu) {
    k_gemm64<<<(n + 63) / 64, 256, 0, stream>>>(A, Wm, bias, C, n, acc, relu);
  };
  auto stats = [&](const float* x, int n) {
    hipMemsetAsync(sums, 0, 128 * 4, stream);
    k_bn_stats<<<512, 256, 0, stream>>>(x, n, sums);
  };
  auto gat_edges = [&](int i, float* fs, float* fd, int n, const int* src, const int* dst,
                       int E, float* out) {
    k_fill<<<256, 256, 0, stream>>>(m_buf, -INFINITY, n);
    hipMemsetAsync(denom, 0, (size_t)n * 4, stream);
    k_gat_edge<<<2048, 256, 0, stream>>>(fs, fd, gat_attn + i * 64, src, dst, e_edge, m_buf, E);
    k_gat_soft<<<2048, 256, 0, stream>>>(e_edge, m_buf, dst, denom, E);
    hipMemsetAsync(out, 0, (size_t)n * 64 * 4, stream);
    k_gat_scat<<<2048, 256, 0, stream>>>(fs, e_edge, denom, src, dst, out, E);
    k_lrelu_ip<<<2048, 256, 0, stream>>>(out, (size_t)n * 64, 0.01f);
  };

  // ---- bn0 ----
  stats(emb, NODES);
  k_bn0_apply<<<2048, 256, 0, stream>>>(emb, e_tot, R(0), sums, bn0_g, bn0_b);

  // ---- gat0: u2i_emb -> R(0) (in-place over uie) ----
  gemm(R(0), gat_Wl + 0 * 4096, gat_bl + 0, R(200000), NUI, 0, 0);
  gemm(R(0), gat_Wr + 0 * 4096, gat_br + 0, R(400000), NUI, 0, 0);
  gat_edges(0, R(200000), R(400000), NUI, u2i_src, u2i_dst, E_u2i, R(0));

  // ---- gat1: iie -> R(0)[:PRED] ----
  gemm(R(0), gat_Wl + 1 * 4096, gat_bl + 64, R(200000), NUI, 0, 0);
  gemm(R(0), gat_Wr + 1 * 4096, gat_br + 64, R(400000), NUI, 0, 0);
  gat_edges(1, R(200000), R(400000), NUI, rc_src, rc_dst, E_rc, R(0));

  // ---- gat2: i2u_emb -> R(300000) ----
  gemm(e_tot, gat_Wl + 2 * 4096, gat_bl + 128, R(200000), PRED, 0, 0);
  gemm(e_tot, gat_Wr + 2 * 4096, gat_br + 128, R(400000), PRED, 0, 0);
  gat_edges(2, R(200000), R(400000), PRED, i2u_src, i2u_dst, E_i2u, R(300000));

  // ---- soc -> R(400000) ----
  k_mask_select<<<2048, 256, 0, stream>>>(R(300000), e_tot, R(400000), PRED);

  // ---- gat3: sie -> R(300000) ----
  gemm(R(400000), gat_Wl + 3 * 4096, gat_bl + 192, R(200000), PRED, 0, 0);
  gemm(R(400000), gat_Wr + 3 * 4096, gat_br + 192, R(500000), PRED, 0, 0);
  gat_edges(3, R(200000), R(500000), PRED, sn_src, sn_dst, E_sn, R(300000));

  // ---- mlp0: user_item -> R(0)[:PRED] (via scratch R(100000)) ----
  gemm(R(0), mlp_W + 0 * 8192, mlp_b + 0, R(100000), PRED, 0, 0);
  gemm(R(300000), mlp_W + 0 * 8192 + 4096, nullptr, R(100000), PRED, 1, 0);
  stats(R(100000), PRED);
  k_bn_apply<<<2048, 256, 0, stream>>>(R(100000), R(0), sums, mlp_g + 0, mlp_beta + 0, PRED, 1);

  // ---- cheb degrees ----
  hipMemsetAsync(deg, 0, (size_t)TOTAL * 4, stream);
  k_deg<<<2048, 256, 0, stream>>>(snn_dst, deg, E_snn);
  k_rsqrt_clip<<<256, 256, 0, stream>>>(deg, TOTAL);

  auto cheb = [&](const float* T0, float* T1, float* T2, float* outC) {
    hipMemsetAsync(T1, 0, (size_t)TOTAL * 64 * 4, stream);
    k_cheb_scat<<<2048, 256, 0, stream>>>(T0, deg, snn_src, snn_dst, T1, E_snn);
    k_cheb_c1<<<2048, 256, 0, stream>>>(T0, T1, (size_t)TOTAL * 64, lam);
    hipMemsetAsync(T2, 0, (size_t)TOTAL * 64 * 4, stream);
    k_cheb_scat<<<2048, 256, 0, stream>>>(T1, deg, snn_src, snn_dst, T2, E_snn);
    k_cheb_c2<<<2048, 256, 0, stream>>>(T0, T1, T2, (size_t)TOTAL * 64, lam);
    gemm(T0, cheb_W + 0,    cheb_b, outC, TOTAL, 0, 0);
    gemm(T1, cheb_W + 4096, nullptr, outC, TOTAL, 1, 0);
    gemm(T2, cheb_W + 8192, nullptr, outC, TOTAL, 1, 1);
  };
  cheb(e_tot, R(100000), R(220000), R(340000));       // h1 -> R(340000)
  cheb(R(340000), R(100000), R(220000), R(460000));   // h2 -> R(460000)

  // ---- gat4: user_social -> R(460000) ----
  gemm(R(460000), gat_Wl + 4 * 4096, gat_bl + 256, R(100000), TOTAL, 0, 0);
  gemm(R(460000), gat_Wr + 4 * 4096, gat_br + 256, R(220000), TOTAL, 0, 0);
  gat_edges(4, R(100000), R(220000), TOTAL, snn_src, snn_dst, E_snn, R(460000));

  // ---- mlp1: h_uP -> R(100000) ----
  gemm(R(0), mlp_W + 1 * 8192, mlp_b + 64, R(100000), PRED, 0, 0);
  gemm(e_tot, mlp_W + 1 * 8192 + 4096, nullptr, R(100000), PRED, 1, 0);
  stats(R(100000), PRED);
  k_bn_apply<<<2048, 256, 0, stream>>>(R(100000), R(100000), sums, mlp_g + 64, mlp_beta + 64, PRED, 1);

  // ---- mlp2: h_uS -> R(200000) ----
  gemm(R(460000), mlp_W + 2 * 8192, mlp_b + 128, R(200000), PRED, 0, 0);
  gemm(e_tot, mlp_W + 2 * 8192 + 4096, nullptr, R(200000), PRED, 1, 0);
  stats(R(200000), PRED);
  k_bn_apply<<<2048, 256, 0, stream>>>(R(200000), R(200000), sums, mlp_g + 128, mlp_beta + 128, PRED, 1);

  // ---- final P ----
  k_softmax_mul<<<2048, 256, 0, stream>>>(R(100000), R(200000), R(300000), PRED);
  gemm(R(300000), mlp_W + 3 * 8192, mlp_b + 192, R(400000), PRED, 0, 0);
  gemm(R(100000), mlp_W + 3 * 8192 + 4096, nullptr, R(400000), PRED, 1, 0);
  stats(R(400000), PRED);
  k_bn_apply<<<2048, 256, 0, stream>>>(R(400000), outP, sums, mlp_g + 192, mlp_beta + 192, PRED, 1);

  // ---- final S ----
  k_softmax_mul<<<2048, 256, 0, stream>>>(R(200000), R(100000), R(300000), PRED);
  gemm(R(300000), mlp_W + 4 * 8192, mlp_b + 256, R(400000), PRED, 0, 0);
  gemm(R(200000), mlp_W + 4 * 8192 + 4096, nullptr, R(400000), PRED, 1, 0);
  stats(R(400000), PRED);
  k_bn_apply<<<2048, 256, 0, stream>>>(R(400000), outS, sums, mlp_g + 256, mlp_beta + 256, PRED, 1);
}